// Round 1
// baseline (126.314 us; speedup 1.0000x reference)
//
#include <hip/hip_runtime.h>

#define Bb 8
#define Ss 2048
#define Dd 1024
#define DKk 512

// ---------------------------------------------------------------------------
// Stage A: partial column sums of x over the sequence axis.
// grid (C chunks, B), block 256 threads; thread t owns float4 lanes d=4t..4t+3.
// Each block streams rows s in [c*rpc, (c+1)*rpc) of batch b — fully coalesced
// 256 threads x 16 B = 4 KiB per row.  Writes one partial row [D] per (b,c).
// ---------------------------------------------------------------------------
__global__ __launch_bounds__(256) void colsum_partial(
    const float* __restrict__ x, float* __restrict__ ws, int C, int rpc) {
    const int c = blockIdx.x;
    const int b = blockIdx.y;
    const int t = threadIdx.x;  // 0..255 -> covers D/4 = 256 float4 slots
    const float4* xb = (const float4*)(x + (size_t)(b * Ss + c * rpc) * Dd);
    float4 acc = make_float4(0.f, 0.f, 0.f, 0.f);
#pragma unroll 8
    for (int s = 0; s < rpc; ++s) {
        float4 v = xb[(size_t)s * (Dd / 4) + t];
        acc.x += v.x; acc.y += v.y; acc.z += v.z; acc.w += v.w;
    }
    float4* wsb = (float4*)(ws + (size_t)(b * C + c) * Dd);
    wsb[t] = acc;
}

// ---------------------------------------------------------------------------
// Stage B0: d_out is re-poisoned to 0xAA before every launch -> initialize
// with the bias so stage B can accumulate atomically on top.
// ---------------------------------------------------------------------------
__global__ __launch_bounds__(256) void init_out(
    const float* __restrict__ bv, float* __restrict__ out) {
    const int i = blockIdx.x * 256 + threadIdx.x;  // 0..B*DK-1
    out[i] = bv[i & (DKk - 1)];
}

// ---------------------------------------------------------------------------
// Stage B: reduce chunk partials -> xbar segment in LDS, then GEMV vs Wv.
// grid (8 d-segments of 128, B), block 512 threads (one per k).
// Wv row reads are coalesced across the 512 k-threads; LDS xbar is a
// broadcast read (no bank conflicts).  8 atomicAdds per output element.
// ---------------------------------------------------------------------------
__global__ __launch_bounds__(512) void gemv_acc(
    const float* __restrict__ ws, const float* __restrict__ Wv,
    float* __restrict__ out, int C) {
    __shared__ float xb[128];
    const int seg = blockIdx.x;  // d-range [seg*128, seg*128+128)
    const int b   = blockIdx.y;
    const int t   = threadIdx.x;
    if (t < 128) {
        const int d = seg * 128 + t;
        float s = 0.f;
        for (int c = 0; c < C; ++c)
            s += ws[(size_t)(b * C + c) * Dd + d];
        xb[t] = s * (1.0f / Ss);  // mean over sequence
    }
    __syncthreads();
    const int k = t;  // 0..511
    const float* wv = Wv + (size_t)(seg * 128) * DKk + k;
    float acc = 0.f;
#pragma unroll 8
    for (int d = 0; d < 128; ++d)
        acc += xb[d] * wv[(size_t)d * DKk];
    atomicAdd(&out[b * DKk + k], acc);
}

extern "C" void kernel_launch(void* const* d_in, const int* in_sizes, int n_in,
                              void* d_out, int out_size, void* d_ws, size_t ws_size,
                              hipStream_t stream) {
    // setup_inputs order: x, Wq, bq, Wk, bk, Wv, bv.
    // Softmax over the QUERY axis makes columns of att sum to 1 exactly, so
    // mean_q(att @ v) == mean_s(v) == mean_s(x) @ Wv + bv.  Only x, Wv, bv matter.
    const float* x  = (const float*)d_in[0];
    const float* Wv = (const float*)d_in[5];
    const float* bv = (const float*)d_in[6];
    float* out = (float*)d_out;   // [B, DK] fp32
    float* ws  = (float*)d_ws;    // partials: [B][C][D] floats

    int C = 64;  // 64 chunks -> 2 MiB workspace; shrink if ws is small
    while (C > 1 && (size_t)Bb * C * Dd * sizeof(float) > ws_size) C >>= 1;
    const int rpc = Ss / C;

    colsum_partial<<<dim3(C, Bb), 256, 0, stream>>>(x, ws, C, rpc);
    init_out<<<dim3((Bb * DKk) / 256), 256, 0, stream>>>(bv, out);
    gemv_acc<<<dim3(8, Bb), 512, 0, stream>>>(ws, Wv, out, C);
}

// Round 2
// 113.207 us; speedup vs baseline: 1.1158x; 1.1158x over previous
//
#include <hip/hip_runtime.h>

#define Bb 8
#define Ss 2048
#define Dd 1024
#define DKk 512
#define CC 128            // chunks per batch -> 1024 stage-A blocks (4/CU, 16 waves/CU)
#define RPC (Ss / CC)     // 16 rows per chunk

// ---------------------------------------------------------------------------
// Stage A: partial column sums of x over the sequence axis + out bias-init.
// 1024 blocks x 256 threads; thread t owns float4 slot t (covers D=1024).
// Each block streams 16 contiguous rows (64 KiB) — fully coalesced.
// Blocks with c==0 also write out[b,:] = bv (d_out is re-poisoned per launch);
// the kernel boundary orders this before stage B's atomicAdds.
// ---------------------------------------------------------------------------
__global__ __launch_bounds__(256) void colsum_partial(
    const float* __restrict__ x, const float* __restrict__ bv,
    float* __restrict__ ws, float* __restrict__ out) {
    const int bid = blockIdx.x;
    const int b   = bid >> 7;        // / CC
    const int c   = bid & (CC - 1);
    const int t   = threadIdx.x;
    const float4* xb = (const float4*)(x + ((size_t)b * Ss + (size_t)c * RPC) * Dd);
    float4 acc = make_float4(0.f, 0.f, 0.f, 0.f);
#pragma unroll
    for (int s = 0; s < RPC; ++s) {
        float4 v = xb[(size_t)s * (Dd / 4) + t];
        acc.x += v.x; acc.y += v.y; acc.z += v.z; acc.w += v.w;
    }
    ((float4*)(ws + ((size_t)b * CC + c) * Dd))[t] = acc;
    if (c == 0) {
        out[b * DKk + t]       = bv[t];
        out[b * DKk + t + 256] = bv[t + 256];
    }
}

// ---------------------------------------------------------------------------
// Stage B: reduce chunk partials -> xbar segment (128 d's) in LDS, then GEMV
// against Wv's matching row band.  Grid 64 blocks = (8 segs x 8 b), 256 thr,
// each thread produces 2 of the 512 k outputs.  Wv reads coalesced; LDS xb
// reads are wave-uniform broadcasts (conflict-free).  8 atomicAdds/output.
// ---------------------------------------------------------------------------
__global__ __launch_bounds__(256) void gemv_acc(
    const float* __restrict__ ws, const float* __restrict__ Wv,
    float* __restrict__ out) {
    __shared__ float xb[128];
    const int seg = blockIdx.x & 7;
    const int b   = blockIdx.x >> 3;
    const int t   = threadIdx.x;
    if (t < 128) {
        const int d = seg * 128 + t;
        float s = 0.f;
#pragma unroll 8
        for (int c = 0; c < CC; ++c)
            s += ws[((size_t)b * CC + c) * Dd + d];
        xb[t] = s * (1.0f / Ss);   // mean over sequence
    }
    __syncthreads();
    const float* wv = Wv + (size_t)(seg * 128) * DKk;
    float a0 = 0.f, a1 = 0.f;
#pragma unroll 8
    for (int d = 0; d < 128; ++d) {
        const float xv = xb[d];
        a0 += xv * wv[(size_t)d * DKk + t];
        a1 += xv * wv[(size_t)d * DKk + t + 256];
    }
    atomicAdd(&out[b * DKk + t],       a0);
    atomicAdd(&out[b * DKk + t + 256], a1);
}

extern "C" void kernel_launch(void* const* d_in, const int* in_sizes, int n_in,
                              void* d_out, int out_size, void* d_ws, size_t ws_size,
                              hipStream_t stream) {
    // setup_inputs order: x, Wq, bq, Wk, bk, Wv, bv.
    // softmax is over the QUERY axis -> every column of att sums to exactly 1,
    // so mean_q(att @ v) == mean_s(v) == (mean_s x) @ Wv + bv.  Q/K are dead.
    const float* x  = (const float*)d_in[0];
    const float* Wv = (const float*)d_in[5];
    const float* bv = (const float*)d_in[6];
    float* out = (float*)d_out;   // [B, DK] fp32
    float* ws  = (float*)d_ws;    // partials: [B][CC][D] floats = 4 MiB

    colsum_partial<<<dim3(Bb * CC), 256, 0, stream>>>(x, bv, ws, out);
    gemv_acc<<<dim3(64), 256, 0, stream>>>(ws, Wv, out);
}